// Round 6
// baseline (906.233 us; speedup 1.0000x reference)
//
#include <hip/hip_runtime.h>
#include <hip/hip_fp16.h>
#include <cstdint>
#include <cstddef>

typedef __attribute__((ext_vector_type(8))) short short8;
typedef __attribute__((ext_vector_type(8))) _Float16 half8;
typedef __attribute__((ext_vector_type(16))) float f32x16;

__device__ __forceinline__ float bf2f(unsigned short u) { return __uint_as_float(((unsigned)u) << 16); }
__device__ __forceinline__ unsigned short f2bf(float f) {
    unsigned u = __float_as_uint(f);
    return (unsigned short)((u + 0x7fffu + ((u >> 16) & 1u)) >> 16);
}
// drain LDS counters only, leave vmcnt live across the barrier
__device__ __forceinline__ void sync_lds() {
    asm volatile("s_waitcnt lgkmcnt(0)\n\ts_barrier" ::: "memory");
}

static constexpr float BN_INV = 0.9999950000374997f;  // 1/sqrt(1+1e-5)

// ---------------- voxelize: packed-f16 scatter-add into (130,130,130,4) channels-last grid --------
__global__ __launch_bounds__(256) void voxelize_kernel(const float4* __restrict__ pts,
                                                       __half2* __restrict__ grid, int N) {
    int i = blockIdx.x * 256 + threadIdx.x;
    if (i >= N) return;
    float4 p = pts[i];
    if (p.x < -32.f || p.x > 32.f || p.y < -32.f || p.y > 32.f || p.z < -32.f || p.z > 32.f) return;
    int cx = min(max((int)floorf((p.x + 32.f) * 2.f), 0), 127);
    int cy = min(max((int)floorf((p.y + 32.f) * 2.f), 0), 127);
    int cz = min(max((int)floorf((p.z + 32.f) * 2.f), 0), 127);
    int idx = ((((cz + 1) * 130) + (cy + 1)) * 130 + (cx + 1)) * 2;  // half2 units
    unsafeAtomicAdd(&grid[idx],     __floats2half2_rn(p.x, p.y));   // global_atomic_pk_add_f16
    unsafeAtomicAdd(&grid[idx + 1], __floats2half2_rn(p.z, p.w));
}

// ---------------- halo-only zeroing (interiors are fully overwritten by conv stores) -------------
__global__ __launch_bounds__(256) void zero_halo(unsigned short* __restrict__ buf, int Xp, int C8, int total) {
    int i = blockIdx.x * 256 + threadIdx.x;
    if (i >= total) return;
    int c8 = i % C8; int t = i / C8;
    int b = t % Xp; t /= Xp;
    int a = t % Xp; int f = t / Xp;
    int X = Xp - 1;
    int z, y, x;
    switch (f) {
        case 0: z = 0; y = a; x = b; break;
        case 1: z = X; y = a; x = b; break;
        case 2: z = a; y = 0; x = b; break;
        case 3: z = a; y = X; x = b; break;
        case 4: z = a; y = b; x = 0; break;
        default: z = a; y = b; x = X; break;
    }
    size_t o = ((((size_t)z * Xp + y) * Xp) + x) * (C8 * 8) + c8 * 8;
    short8 zz = {};
    *(short8*)(buf + o) = zz;
}
// y/x shells only (for the O1s z-slab buffer)
__global__ __launch_bounds__(256) void zero_halo_yx(unsigned short* __restrict__ buf, int Zn, int Xp,
                                                    int C8, int total) {
    int i = blockIdx.x * 256 + threadIdx.x;
    if (i >= total) return;
    int c8 = i % C8; int t = i / C8;
    int b = t % Xp; t /= Xp;
    int z = t % Zn; int f = t / Zn;
    int X = Xp - 1;
    int y, x;
    switch (f) {
        case 0: y = 0; x = b; break;
        case 1: y = X; x = b; break;
        case 2: y = b; x = 0; break;
        default: y = b; x = X; break;
    }
    size_t o = ((((size_t)z * Xp + y) * Xp) + x) * (C8 * 8) + c8 * 8;
    short8 zz = {};
    *(short8*)(buf + o) = zz;
}

// ---------------- weight repacks (fold BN gamma scale) ----------------
__global__ __launch_bounds__(256) void repack_w(const float* __restrict__ w, const float* __restrict__ g,
                                                unsigned short* __restrict__ o, int Co, int CI) {
    int i = blockIdx.x * 256 + threadIdx.x;
    int total = 27 * Co * CI;
    if (i >= total) return;
    int ci = i % CI;
    int t = i / CI;
    int co = t % Co;
    int k = t / Co;
    float v = w[((size_t)(co * CI + ci)) * 27 + k] * g[co] * BN_INV;
    o[i] = f2bf(v);
}
// conv1 MFMA: out[pair p(9)][co(32)][k16] f16, k16 = dx*4+ci for k16<12 else 0
__global__ __launch_bounds__(256) void repack_w1m(const float* __restrict__ w, const float* __restrict__ g,
                                                  unsigned short* __restrict__ o) {
    int i = blockIdx.x * 256 + threadIdx.x;
    if (i >= 9 * 32 * 16) return;
    int k16 = i & 15;
    int co = (i >> 4) & 31;
    int p = i >> 9;
    float v = 0.f;
    if (k16 < 12) {
        int dx = k16 >> 2, ci = k16 & 3;
        int dz = p / 3, dy = p % 3;
        v = w[(co * 4 + ci) * 27 + dz * 9 + dy * 3 + dx] * g[co] * BN_INV;
    }
    o[i] = __half_as_ushort(__float2half(v));
}

// ---------------- conv1 via MFMA 32x32x16_f16, all 27 fragment loads preissued ----------------
__global__ __launch_bounds__(256) void conv1_mfma(
    const unsigned short* __restrict__ in, const unsigned short* __restrict__ wa,
    const float* __restrict__ beta, unsigned short* __restrict__ out,
    int zstart, int r0) {
    const int tid = threadIdx.x;
    const int l31 = tid & 31;
    const int lh = (tid >> 5) & 1;
    const int wv = tid >> 6;
    int v = blockIdx.x * 128 + wv * 32 + l31;
    int x = v & 127;
    int y = (v >> 7) & 127;
    int z = zstart + (v >> 14);

    const unsigned short* base = in + ((z * 130 + y) * 130 + x) * 4 + lh * 8;
    uint2 d0[9], d1[9];
    half8 a[9];
#pragma unroll
    for (int p = 0; p < 9; ++p) {
        int dz = p / 3, dy = p % 3;
        const unsigned short* rp = base + (dz * 130 + dy) * 520;
        d0[p] = *(const uint2*)(rp);
        d1[p] = *(const uint2*)(rp + 4);  // lh=1: k12-15 garbage, annihilated by A zeros
        a[p] = *(const half8*)(wa + (p * 32 + l31) * 16 + lh * 8);
    }
    f32x16 acc = {0.f};
#pragma unroll
    for (int p = 0; p < 9; ++p) {
        uint4 braw = {d0[p].x, d0[p].y, d1[p].x, d1[p].y};
        half8 b = *(half8*)&braw;
        acc = __builtin_amdgcn_mfma_f32_32x32x16_f16(a[p], b, acc, 0, 0, 0);
    }
    int r = z - zstart + r0;
    int ob = ((r * 130 + (y + 1)) * 130 + (x + 1)) * 32;
#pragma unroll
    for (int g = 0; g < 4; ++g) {
        int cb = 4 * lh + 8 * g;
        float4 bt = *(const float4*)(beta + cb);
        ushort4 u;
        u.x = f2bf(fmaxf(acc[g * 4 + 0] + bt.x, 0.f));
        u.y = f2bf(fmaxf(acc[g * 4 + 1] + bt.y, 0.f));
        u.z = f2bf(fmaxf(acc[g * 4 + 2] + bt.z, 0.f));
        u.w = f2bf(fmaxf(acc[g * 4 + 3] + bt.w, 0.f));
        *(ushort4*)(out + ob + cb) = u;
    }
}

// ---------------- convs 2-6: x-extended-row staging, A direct from L1, 9*NCC stages -------------
// Block: 4 waves, tile 64co x 128vox. Per stage (dz,dy,ci-chunk): stage x-extended rows of B in
// LDS (dx handled as LDS row offset), A fragments loaded global->VGPR (L1-resident). Wave w:
// co half (w&1), vox half (w>>1); 2 acc tiles over vox; 24 (KC=64) or 12 (KC=32) MFMA per stage.
template <int CI, int KC, int S, int D>
__global__ __launch_bounds__(256) void conv_mfma(
    const unsigned short* __restrict__ in, const unsigned short* __restrict__ wb,
    const float* __restrict__ beta, unsigned short* __restrict__ out,
    int Xp, int Xpo, int Co, int zin_base, int v_off) {

    constexpr int lgD = (D == 64) ? 6 : 5;
    constexpr int NR = 128 / D;          // y-rows per block tile
    constexpr int Lx = (D - 1) * S + 3;  // x-extended row length (padded coords)
    constexpr int KCp = KC + 8;
    constexpr int OPV = KC / 8;          // 16B octets per voxel
    constexpr int OPR = Lx * OPV;        // octets per row
    constexpr int OCT = NR * OPR;        // octets per stage
    constexpr int NB4 = OCT >> 8;        // full staging loads per thread (=4)
    constexpr int TAIL = OCT - NB4 * 256;
    constexpr int NCH = KC / 16;
    constexpr int NCC = CI / KC;
    constexpr int STOT = 9 * NCC;
    constexpr int RT = NR * Lx;          // LDS voxel-rows per buffer

    __shared__ __align__(16) short sB[2 * RT * KCp];

    const int tid = threadIdx.x;
    const int l31 = tid & 31;
    const int lh = (tid >> 5) & 1;
    const int wv = tid >> 6;
    const int coh = (wv & 1) * 32;
    const int vh = (wv >> 1) * 64;
    const int co0 = blockIdx.x * 64;

    const int v0 = v_off + blockIdx.y * 128;
    const int z0 = v0 >> (2 * lgD);
    const int y0 = (v0 >> lgD) & (D - 1);

    // staging thread -> (row, x, octet)
    int srow[NB4 + 1], sgi[NB4 + 1], sli[NB4 + 1];
#pragma unroll
    for (int j = 0; j <= NB4; ++j) {
        int o = tid + j * 256;
        int r = o / OPR;
        int rem = o - r * OPR;
        int i = rem / OPV;
        int ov = rem - i * OPV;
        srow[j] = r;
        sgi[j] = i * CI + ov * 8;
        sli[j] = (r * Lx + i) * KCp + ov * 8;
    }
    // per-lane fragment addresses
    int bfr[2];
#pragma unroll
    for (int vt = 0; vt < 2; ++vt) {
        int lv = vh + vt * 32 + l31;
        int p = lv & (D - 1);
        int r = lv >> lgD;
        bfr[vt] = (r * Lx + p * S) * KCp + lh * 8;
    }
    const int aw = (co0 + coh + l31) * CI + lh * 8;

    short8 rB[2][NB4 + 1];

    auto loadStage = [&](int s, int slot) {
        int k9 = s / NCC;
        int c0 = (s - k9 * NCC) * KC;
        int dz = k9 / 3, dy = k9 - dz * 3;
        int zrow = z0 * S + dz - zin_base;
#pragma unroll
        for (int j = 0; j < NB4; ++j) {
            int rb = ((zrow * Xp + (y0 + srow[j]) * S + dy) * Xp) * CI + c0;
            rB[slot][j] = *(const short8*)(in + rb + sgi[j]);
        }
        if (TAIL && tid < TAIL) {
            int rb = ((zrow * Xp + (y0 + srow[NB4]) * S + dy) * Xp) * CI + c0;
            rB[slot][NB4] = *(const short8*)(in + rb + sgi[NB4]);
        }
    };
    auto storeLDS = [&](int slot, int buf) {
        short* d = sB + buf * RT * KCp;
#pragma unroll
        for (int j = 0; j < NB4; ++j) *(short8*)(d + sli[j]) = rB[slot][j];
        if (TAIL && tid < TAIL) *(short8*)(d + sli[NB4]) = rB[slot][NB4];
    };

    f32x16 acc0 = {0.f}, acc1 = {0.f};

    loadStage(0, 0);
    loadStage(1, 1);
    storeLDS(0, 0);
    sync_lds();

#pragma unroll
    for (int s = 0; s < STOT; ++s) {
        if (s + 2 < STOT) loadStage(s + 2, s & 1);
        {
            int k9 = s / NCC;
            int c0 = (s - k9 * NCC) * KC;
            const short* pB = sB + (s & 1) * RT * KCp;
            size_t kwb = (size_t)(k9 * 3) * Co * CI + c0;
#pragma unroll
            for (int dx = 0; dx < 3; ++dx) {
#pragma unroll
                for (int c = 0; c < NCH; ++c) {
                    short8 av = *(const short8*)(wb + kwb + (size_t)dx * Co * CI + aw + c * 16);
                    short8 b0 = *(const short8*)(pB + bfr[0] + dx * KCp + c * 16);
                    short8 b1 = *(const short8*)(pB + bfr[1] + dx * KCp + c * 16);
                    acc0 = __builtin_amdgcn_mfma_f32_32x32x16_bf16(av, b0, acc0, 0, 0, 0);
                    acc1 = __builtin_amdgcn_mfma_f32_32x32x16_bf16(av, b1, acc1, 0, 0, 0);
                }
            }
        }
        if (s + 1 < STOT) {
            storeLDS((s + 1) & 1, (s + 1) & 1);
            sync_lds();
        }
    }

    // epilogue: relu(acc + beta) -> bf16, channels-last padded store (layout verified R4/R5)
#pragma unroll
    for (int vt = 0; vt < 2; ++vt) {
        const f32x16& a = vt ? acc1 : acc0;
        int lv = vh + vt * 32 + l31;
        int x = lv & (D - 1);
        int yv = y0 + (lv >> lgD);
        size_t ob = (((size_t)(z0 + 1) * Xpo + (yv + 1)) * Xpo + (x + 1)) * Co + co0 + coh;
#pragma unroll
        for (int g = 0; g < 4; ++g) {
            int cb = 4 * lh + 8 * g;
            float4 bt = *(const float4*)(beta + co0 + coh + cb);
            ushort4 u;
            u.x = f2bf(fmaxf(a[g * 4 + 0] + bt.x, 0.f));
            u.y = f2bf(fmaxf(a[g * 4 + 1] + bt.y, 0.f));
            u.z = f2bf(fmaxf(a[g * 4 + 2] + bt.z, 0.f));
            u.w = f2bf(fmaxf(a[g * 4 + 3] + bt.w, 0.f));
            *(ushort4*)(out + ob + cb) = u;
        }
    }
}

// ---------------- BEV max over y: O6p (34,34,34,256) -> bev[(z*32+x)*256+c] f32 ----------------
__global__ __launch_bounds__(256) void bev_max_kernel(const unsigned short* __restrict__ feat,
                                                      float* __restrict__ bev) {
    int z = blockIdx.x >> 5;
    int x = blockIdx.x & 31;
    int c = threadIdx.x;
    const unsigned short* p = feat + ((((z + 1) * 34) + 1) * 34 + (x + 1)) * 256 + c;
    float mx = 0.f;  // post-ReLU values are >= 0
#pragma unroll
    for (int y = 0; y < 32; ++y) mx = fmaxf(mx, bf2f(p[y * 34 * 256]));
    bev[(z * 32 + x) * 256 + c] = mx;
}

// ---------------- bilinear resize 32x32 -> 200x200, half-pixel, edge clamp ----------------
__global__ __launch_bounds__(256) void resize_kernel(const float* __restrict__ bev,
                                                     float* __restrict__ out) {
    int i = blockIdx.x * 256 + threadIdx.x;
    if (i >= 256 * 200 * 200) return;
    int ox = i % 200;
    int t = i / 200;
    int oy = t % 200;
    int c = t / 200;
    const float sc = 32.0f / 200.0f;
    float fy = (oy + 0.5f) * sc - 0.5f;
    float fx = (ox + 0.5f) * sc - 0.5f;
    float fy0 = floorf(fy), fx0 = floorf(fx);
    float ty = fy - fy0, tx = fx - fx0;
    int y0 = min(max((int)fy0, 0), 31), y1 = min(max((int)fy0 + 1, 0), 31);
    int x0 = min(max((int)fx0, 0), 31), x1 = min(max((int)fx0 + 1, 0), 31);
    float v00 = bev[(y0 * 32 + x0) * 256 + c], v01 = bev[(y0 * 32 + x1) * 256 + c];
    float v10 = bev[(y1 * 32 + x0) * 256 + c], v11 = bev[(y1 * 32 + x1) * 256 + c];
    float top = v00 + tx * (v01 - v00);
    float bot = v10 + tx * (v11 - v10);
    out[i] = top + ty * (bot - top);
}

extern "C" void kernel_launch(void* const* d_in, const int* in_sizes, int n_in,
                              void* d_out, int out_size, void* d_ws, size_t ws_size,
                              hipStream_t stream) {
    const float* points = (const float*)d_in[0];
    int N = in_sizes[0] / 4;
    const float *W[6], *G[6], *B[6];
    for (int i = 0; i < 6; ++i) {
        W[i] = (const float*)d_in[1 + 3 * i];
        G[i] = (const float*)d_in[2 + 3 * i];
        B[i] = (const float*)d_in[3 + 3 * i];
    }

    // ---- workspace layout (bytes), peak ~144 MiB ----
    char* ws = (char*)d_ws;
    const size_t MiB = 1ull << 20;
    unsigned short* gridH = (unsigned short*)(ws);               // f16 (130^3,4) = 17,576,000 B
    unsigned short* O1s = (unsigned short*)(ws + 36 * MiB);      // 65*130*130*32*2 = 70,304,000
    unsigned short* O2p = (unsigned short*)(ws + 104 * MiB);     // 66^3*64*2 = 36,799,488
    unsigned short* O3p = (unsigned short*)(ws);                 // 36,799,488 (over dead gridH)
    unsigned short* O4p = (unsigned short*)(ws + 37 * MiB);      // 34^3*128*2 = 10,061,824
    unsigned short* O5p = (unsigned short*)(ws + 48 * MiB);      // 10,061,824
    unsigned short* O6p = (unsigned short*)(ws + 59 * MiB);      // 34^3*256*2 = 20,123,648
    float* bev = (float*)(ws + 80 * MiB);                        // 1,048,576
    unsigned short* wc1 = (unsigned short*)(ws + 140 * MiB);     // 9,216
    unsigned short* wb2 = (unsigned short*)(ws + 140 * MiB + 16384);
    unsigned short* wb3 = wb2 + 27 * 64 * 32;
    unsigned short* wb4 = wb3 + 27 * 64 * 64;
    unsigned short* wb5 = wb4 + 27 * 128 * 64;
    unsigned short* wb6 = wb5 + 27 * 128 * 128;

    // weight repacks (independent of activations)
    repack_w1m<<<18, 256, 0, stream>>>(W[0], G[0], wc1);
    repack_w<<<216, 256, 0, stream>>>(W[1], G[1], wb2, 64, 32);
    repack_w<<<432, 256, 0, stream>>>(W[2], G[2], wb3, 64, 64);
    repack_w<<<864, 256, 0, stream>>>(W[3], G[3], wb4, 128, 64);
    repack_w<<<1728, 256, 0, stream>>>(W[4], G[4], wb5, 128, 128);
    repack_w<<<3456, 256, 0, stream>>>(W[5], G[5], wb6, 256, 128);

    // voxelize (f16 pk atomics) — grid must be fully zeroed for accumulation
    hipMemsetAsync(gridH, 0, 17576000, stream);
    zero_halo<<<817, 256, 0, stream>>>(O2p, 66, 8, 6 * 66 * 66 * 8);
    voxelize_kernel<<<(N + 255) / 256, 256, 0, stream>>>((const float4*)points, (__half2*)gridH, N);

    // O1s: row 0 full zero + y/x shells of all 65 rows
    hipMemsetAsync(O1s, 0, 1081600, stream);
    zero_halo_yx<<<529, 256, 0, stream>>>(O1s, 65, 130, 4, 4 * 65 * 130 * 4);

    // conv1/conv2 in two z-slabs (O1s holds 65 padded-z rows)
    conv1_mfma<<<8192, 256, 0, stream>>>(gridH, wc1, B[0], O1s, 0, 1);
    conv_mfma<32, 32, 2, 64><<<dim3(1, 1024), 256, 0, stream>>>(O1s, wb2, B[1], O2p, 130, 66, 64, 0, 0);
    conv1_mfma<<<8320, 256, 0, stream>>>(gridH, wc1, B[0], O1s, 63, 0);
    conv_mfma<32, 32, 2, 64><<<dim3(1, 1024), 256, 0, stream>>>(O1s, wb2, B[1], O2p, 130, 66, 64, 64, 131072);

    // remaining buffers become free only after conv2-h2 (aliasing over gridH/O1s)
    zero_halo<<<817, 256, 0, stream>>>(O3p, 66, 8, 6 * 66 * 66 * 8);
    zero_halo<<<434, 256, 0, stream>>>(O4p, 34, 16, 6 * 34 * 34 * 16);
    zero_halo<<<434, 256, 0, stream>>>(O5p, 34, 16, 6 * 34 * 34 * 16);
    zero_halo<<<868, 256, 0, stream>>>(O6p, 34, 32, 6 * 34 * 34 * 32);

    // conv3: 64->64, s1, 64^3
    conv_mfma<64, 64, 1, 64><<<dim3(1, 2048), 256, 0, stream>>>(O2p, wb3, B[2], O3p, 66, 66, 64, 0, 0);
    // conv4: 64->128, s2, 64^3 -> 32^3
    conv_mfma<64, 32, 2, 32><<<dim3(2, 256), 256, 0, stream>>>(O3p, wb4, B[3], O4p, 66, 34, 128, 0, 0);
    // conv5: 128->128, s1, 32^3
    conv_mfma<128, 64, 1, 32><<<dim3(2, 256), 256, 0, stream>>>(O4p, wb5, B[4], O5p, 34, 34, 128, 0, 0);
    // conv6: 128->256, s1, 32^3
    conv_mfma<128, 64, 1, 32><<<dim3(4, 256), 256, 0, stream>>>(O5p, wb6, B[5], O6p, 34, 34, 256, 0, 0);

    bev_max_kernel<<<1024, 256, 0, stream>>>(O6p, bev);
    resize_kernel<<<40000, 256, 0, stream>>>(bev, (float*)d_out);
}

// Round 7
// 849.318 us; speedup vs baseline: 1.0670x; 1.0670x over previous
//
#include <hip/hip_runtime.h>
#include <hip/hip_fp16.h>
#include <cstdint>
#include <cstddef>

typedef __attribute__((ext_vector_type(8))) short short8;
typedef __attribute__((ext_vector_type(8))) _Float16 half8;
typedef __attribute__((ext_vector_type(16))) float f32x16;

__device__ __forceinline__ float bf2f(unsigned short u) { return __uint_as_float(((unsigned)u) << 16); }
__device__ __forceinline__ unsigned short f2bf(float f) {
    unsigned u = __float_as_uint(f);
    return (unsigned short)((u + 0x7fffu + ((u >> 16) & 1u)) >> 16);
}
// drain LDS counters only, leave vmcnt live across the barrier
__device__ __forceinline__ void sync_lds() {
    asm volatile("s_waitcnt lgkmcnt(0)\n\ts_barrier" ::: "memory");
}

static constexpr float BN_INV = 0.9999950000374997f;  // 1/sqrt(1+1e-5)

// ---------------- voxelize: packed-f16 scatter-add into (130,130,130,4) channels-last grid --------
__global__ __launch_bounds__(256) void voxelize_kernel(const float4* __restrict__ pts,
                                                       __half2* __restrict__ grid, int N) {
    int i = blockIdx.x * 256 + threadIdx.x;
    if (i >= N) return;
    float4 p = pts[i];
    if (p.x < -32.f || p.x > 32.f || p.y < -32.f || p.y > 32.f || p.z < -32.f || p.z > 32.f) return;
    int cx = min(max((int)floorf((p.x + 32.f) * 2.f), 0), 127);
    int cy = min(max((int)floorf((p.y + 32.f) * 2.f), 0), 127);
    int cz = min(max((int)floorf((p.z + 32.f) * 2.f), 0), 127);
    int idx = ((((cz + 1) * 130) + (cy + 1)) * 130 + (cx + 1)) * 2;  // half2 units
    unsafeAtomicAdd(&grid[idx],     __floats2half2_rn(p.x, p.y));   // global_atomic_pk_add_f16
    unsafeAtomicAdd(&grid[idx + 1], __floats2half2_rn(p.z, p.w));
}

// ---------------- halo-only zeroing (interiors are fully overwritten by conv stores) -------------
__global__ __launch_bounds__(256) void zero_halo(unsigned short* __restrict__ buf, int Xp, int C8, int total) {
    int i = blockIdx.x * 256 + threadIdx.x;
    if (i >= total) return;
    int c8 = i % C8; int t = i / C8;
    int b = t % Xp; t /= Xp;
    int a = t % Xp; int f = t / Xp;
    int X = Xp - 1;
    int z, y, x;
    switch (f) {
        case 0: z = 0; y = a; x = b; break;
        case 1: z = X; y = a; x = b; break;
        case 2: z = a; y = 0; x = b; break;
        case 3: z = a; y = X; x = b; break;
        case 4: z = a; y = b; x = 0; break;
        default: z = a; y = b; x = X; break;
    }
    size_t o = ((((size_t)z * Xp + y) * Xp) + x) * (C8 * 8) + c8 * 8;
    short8 zz = {};
    *(short8*)(buf + o) = zz;
}
// y/x shells only (for the O1s z-slab buffer)
__global__ __launch_bounds__(256) void zero_halo_yx(unsigned short* __restrict__ buf, int Zn, int Xp,
                                                    int C8, int total) {
    int i = blockIdx.x * 256 + threadIdx.x;
    if (i >= total) return;
    int c8 = i % C8; int t = i / C8;
    int b = t % Xp; t /= Xp;
    int z = t % Zn; int f = t / Zn;
    int X = Xp - 1;
    int y, x;
    switch (f) {
        case 0: y = 0; x = b; break;
        case 1: y = X; x = b; break;
        case 2: y = b; x = 0; break;
        default: y = b; x = X; break;
    }
    size_t o = ((((size_t)z * Xp + y) * Xp) + x) * (C8 * 8) + c8 * 8;
    short8 zz = {};
    *(short8*)(buf + o) = zz;
}

// ---------------- weight repacks (fold BN gamma scale) ----------------
__global__ __launch_bounds__(256) void repack_w(const float* __restrict__ w, const float* __restrict__ g,
                                                unsigned short* __restrict__ o, int Co, int CI) {
    int i = blockIdx.x * 256 + threadIdx.x;
    int total = 27 * Co * CI;
    if (i >= total) return;
    int ci = i % CI;
    int t = i / CI;
    int co = t % Co;
    int k = t / Co;
    float v = w[((size_t)(co * CI + ci)) * 27 + k] * g[co] * BN_INV;
    o[i] = f2bf(v);
}
// conv1 MFMA: out[pair p(9)][co(32)][k16] f16, k16 = dx*4+ci for k16<12 else 0
__global__ __launch_bounds__(256) void repack_w1m(const float* __restrict__ w, const float* __restrict__ g,
                                                  unsigned short* __restrict__ o) {
    int i = blockIdx.x * 256 + threadIdx.x;
    if (i >= 9 * 32 * 16) return;
    int k16 = i & 15;
    int co = (i >> 4) & 31;
    int p = i >> 9;
    float v = 0.f;
    if (k16 < 12) {
        int dx = k16 >> 2, ci = k16 & 3;
        int dz = p / 3, dy = p % 3;
        v = w[(co * 4 + ci) * 27 + dz * 9 + dy * 3 + dx] * g[co] * BN_INV;
    }
    o[i] = __half_as_ushort(__float2half(v));
}

// ---------------- conv1 via MFMA 32x32x16_f16, all 27 fragment loads preissued ----------------
__global__ __launch_bounds__(256) void conv1_mfma(
    const unsigned short* __restrict__ in, const unsigned short* __restrict__ wa,
    const float* __restrict__ beta, unsigned short* __restrict__ out,
    int zstart, int r0) {
    const int tid = threadIdx.x;
    const int l31 = tid & 31;
    const int lh = (tid >> 5) & 1;
    const int wv = tid >> 6;
    int v = blockIdx.x * 128 + wv * 32 + l31;
    int x = v & 127;
    int y = (v >> 7) & 127;
    int z = zstart + (v >> 14);

    const unsigned short* base = in + ((z * 130 + y) * 130 + x) * 4 + lh * 8;
    uint2 d0[9], d1[9];
    half8 a[9];
#pragma unroll
    for (int p = 0; p < 9; ++p) {
        int dz = p / 3, dy = p % 3;
        const unsigned short* rp = base + (dz * 130 + dy) * 520;
        d0[p] = *(const uint2*)(rp);
        d1[p] = *(const uint2*)(rp + 4);  // lh=1: k12-15 garbage, annihilated by A zeros
        a[p] = *(const half8*)(wa + (p * 32 + l31) * 16 + lh * 8);
    }
    f32x16 acc = {0.f};
#pragma unroll
    for (int p = 0; p < 9; ++p) {
        uint4 braw = {d0[p].x, d0[p].y, d1[p].x, d1[p].y};
        half8 b = *(half8*)&braw;
        acc = __builtin_amdgcn_mfma_f32_32x32x16_f16(a[p], b, acc, 0, 0, 0);
    }
    int r = z - zstart + r0;
    int ob = ((r * 130 + (y + 1)) * 130 + (x + 1)) * 32;
#pragma unroll
    for (int g = 0; g < 4; ++g) {
        int cb = 4 * lh + 8 * g;
        float4 bt = *(const float4*)(beta + cb);
        ushort4 u;
        u.x = f2bf(fmaxf(acc[g * 4 + 0] + bt.x, 0.f));
        u.y = f2bf(fmaxf(acc[g * 4 + 1] + bt.y, 0.f));
        u.z = f2bf(fmaxf(acc[g * 4 + 2] + bt.z, 0.f));
        u.w = f2bf(fmaxf(acc[g * 4 + 3] + bt.w, 0.f));
        *(ushort4*)(out + ob + cb) = u;
    }
}

// ---------------- convs 2-6: x-extended-row B staging + A register double-buffer ----------------
// Per stage (dz,dy,ci-chunk): B rows staged via LDS double-buffer; A fragments prefetched into
// registers ONE STAGE AHEAD and issued BEFORE the B(s+2) prefetch, so no vmcnt wait in the MFMA
// loop ever drains the lookahead (vmcnt is order/count-based). dx = LDS row offset.
template <int CI, int KC, int S, int D>
__global__ __launch_bounds__(256) void conv_mfma(
    const unsigned short* __restrict__ in, const unsigned short* __restrict__ wb,
    const float* __restrict__ beta, unsigned short* __restrict__ out,
    int Xp, int Xpo, int Co, int zin_base, int v_off) {

    constexpr int lgD = (D == 64) ? 6 : 5;
    constexpr int NR = 128 / D;          // y-rows per block tile
    constexpr int Lx = (D - 1) * S + 3;  // x-extended row length (padded coords)
    constexpr int KCp = KC + 8;
    constexpr int OPV = KC / 8;          // 16B octets per voxel
    constexpr int OPR = Lx * OPV;        // octets per row
    constexpr int OCT = NR * OPR;        // octets per stage
    constexpr int NB4 = OCT >> 8;        // full staging loads per thread (=4)
    constexpr int TAIL = OCT - NB4 * 256;
    constexpr int NCH = KC / 16;
    constexpr int NCC = CI / KC;
    constexpr int STOT = 9 * NCC;
    constexpr int RT = NR * Lx;          // LDS voxel-rows per buffer

    __shared__ __align__(16) short sB[2 * RT * KCp];

    const int tid = threadIdx.x;
    const int l31 = tid & 31;
    const int lh = (tid >> 5) & 1;
    const int wv = tid >> 6;
    const int coh = (wv & 1) * 32;
    const int vh = (wv >> 1) * 64;
    const int co0 = blockIdx.x * 64;

    const int v0 = v_off + blockIdx.y * 128;
    const int z0 = v0 >> (2 * lgD);
    const int y0 = (v0 >> lgD) & (D - 1);

    // staging thread -> (row, x, octet)
    int srow[NB4 + 1], sgi[NB4 + 1], sli[NB4 + 1];
#pragma unroll
    for (int j = 0; j <= NB4; ++j) {
        int o = tid + j * 256;
        int r = o / OPR;
        int rem = o - r * OPR;
        int i = rem / OPV;
        int ov = rem - i * OPV;
        srow[j] = r;
        sgi[j] = i * CI + ov * 8;
        sli[j] = (r * Lx + i) * KCp + ov * 8;
    }
    // per-lane fragment addresses
    int bfr[2];
#pragma unroll
    for (int vt = 0; vt < 2; ++vt) {
        int lv = vh + vt * 32 + l31;
        int p = lv & (D - 1);
        int r = lv >> lgD;
        bfr[vt] = (r * Lx + p * S) * KCp + lh * 8;
    }
    const int aw = (co0 + coh + l31) * CI + lh * 8;

    short8 rB[2][NB4 + 1];
    short8 rA[2][3][NCH];

    auto loadA = [&](int s, int slot) {
        int k9 = s / NCC;
        int c0 = (s - k9 * NCC) * KC;
        size_t kwb = (size_t)(k9 * 3) * Co * CI + c0 + aw;
#pragma unroll
        for (int dx = 0; dx < 3; ++dx)
#pragma unroll
            for (int c = 0; c < NCH; ++c)
                rA[slot][dx][c] = *(const short8*)(wb + kwb + (size_t)dx * Co * CI + c * 16);
    };
    auto loadStage = [&](int s, int slot) {
        int k9 = s / NCC;
        int c0 = (s - k9 * NCC) * KC;
        int dz = k9 / 3, dy = k9 - dz * 3;
        int zrow = z0 * S + dz - zin_base;
#pragma unroll
        for (int j = 0; j < NB4; ++j) {
            int rb = ((zrow * Xp + (y0 + srow[j]) * S + dy) * Xp) * CI + c0;
            rB[slot][j] = *(const short8*)(in + rb + sgi[j]);
        }
        if (TAIL && tid < TAIL) {
            int rb = ((zrow * Xp + (y0 + srow[NB4]) * S + dy) * Xp) * CI + c0;
            rB[slot][NB4] = *(const short8*)(in + rb + sgi[NB4]);
        }
    };
    auto storeLDS = [&](int slot, int buf) {
        short* d = sB + buf * RT * KCp;
#pragma unroll
        for (int j = 0; j < NB4; ++j) *(short8*)(d + sli[j]) = rB[slot][j];
        if (TAIL && tid < TAIL) *(short8*)(d + sli[NB4]) = rB[slot][NB4];
    };

    f32x16 acc0 = {0.f}, acc1 = {0.f};

    loadA(0, 0);          // A(0) first: its wait never drains later loads
    loadStage(0, 0);
    loadStage(1, 1);
    storeLDS(0, 0);
    sync_lds();

#pragma unroll
    for (int s = 0; s < STOT; ++s) {
        if (s + 1 < STOT) loadA(s + 1, (s + 1) & 1);   // A ahead of B prefetch (vmcnt ordering)
        if (s + 2 < STOT) loadStage(s + 2, s & 1);
        {
            const short* pB = sB + (s & 1) * RT * KCp;
#pragma unroll
            for (int dx = 0; dx < 3; ++dx) {
#pragma unroll
                for (int c = 0; c < NCH; ++c) {
                    short8 av = rA[s & 1][dx][c];
                    short8 b0 = *(const short8*)(pB + bfr[0] + dx * KCp + c * 16);
                    short8 b1 = *(const short8*)(pB + bfr[1] + dx * KCp + c * 16);
                    acc0 = __builtin_amdgcn_mfma_f32_32x32x16_bf16(av, b0, acc0, 0, 0, 0);
                    acc1 = __builtin_amdgcn_mfma_f32_32x32x16_bf16(av, b1, acc1, 0, 0, 0);
                }
            }
        }
        if (s + 1 < STOT) {
            storeLDS((s + 1) & 1, (s + 1) & 1);
            sync_lds();
        }
    }

    // epilogue: relu(acc + beta) -> bf16, channels-last padded store (layout verified R4/R5)
#pragma unroll
    for (int vt = 0; vt < 2; ++vt) {
        const f32x16& a = vt ? acc1 : acc0;
        int lv = vh + vt * 32 + l31;
        int x = lv & (D - 1);
        int yv = y0 + (lv >> lgD);
        size_t ob = (((size_t)(z0 + 1) * Xpo + (yv + 1)) * Xpo + (x + 1)) * Co + co0 + coh;
#pragma unroll
        for (int g = 0; g < 4; ++g) {
            int cb = 4 * lh + 8 * g;
            float4 bt = *(const float4*)(beta + co0 + coh + cb);
            ushort4 u;
            u.x = f2bf(fmaxf(a[g * 4 + 0] + bt.x, 0.f));
            u.y = f2bf(fmaxf(a[g * 4 + 1] + bt.y, 0.f));
            u.z = f2bf(fmaxf(a[g * 4 + 2] + bt.z, 0.f));
            u.w = f2bf(fmaxf(a[g * 4 + 3] + bt.w, 0.f));
            *(ushort4*)(out + ob + cb) = u;
        }
    }
}

// ---------------- BEV max over y: O6p (34,34,34,256) -> bev[(z*32+x)*256+c] f32 ----------------
__global__ __launch_bounds__(256) void bev_max_kernel(const unsigned short* __restrict__ feat,
                                                      float* __restrict__ bev) {
    int z = blockIdx.x >> 5;
    int x = blockIdx.x & 31;
    int c = threadIdx.x;
    const unsigned short* p = feat + ((((z + 1) * 34) + 1) * 34 + (x + 1)) * 256 + c;
    float mx = 0.f;  // post-ReLU values are >= 0
#pragma unroll
    for (int y = 0; y < 32; ++y) mx = fmaxf(mx, bf2f(p[y * 34 * 256]));
    bev[(z * 32 + x) * 256 + c] = mx;
}

// ---------------- bilinear resize 32x32 -> 200x200, half-pixel, edge clamp ----------------
__global__ __launch_bounds__(256) void resize_kernel(const float* __restrict__ bev,
                                                     float* __restrict__ out) {
    int i = blockIdx.x * 256 + threadIdx.x;
    if (i >= 256 * 200 * 200) return;
    int ox = i % 200;
    int t = i / 200;
    int oy = t % 200;
    int c = t / 200;
    const float sc = 32.0f / 200.0f;
    float fy = (oy + 0.5f) * sc - 0.5f;
    float fx = (ox + 0.5f) * sc - 0.5f;
    float fy0 = floorf(fy), fx0 = floorf(fx);
    float ty = fy - fy0, tx = fx - fx0;
    int y0 = min(max((int)fy0, 0), 31), y1 = min(max((int)fy0 + 1, 0), 31);
    int x0 = min(max((int)fx0, 0), 31), x1 = min(max((int)fx0 + 1, 0), 31);
    float v00 = bev[(y0 * 32 + x0) * 256 + c], v01 = bev[(y0 * 32 + x1) * 256 + c];
    float v10 = bev[(y1 * 32 + x0) * 256 + c], v11 = bev[(y1 * 32 + x1) * 256 + c];
    float top = v00 + tx * (v01 - v00);
    float bot = v10 + tx * (v11 - v10);
    out[i] = top + ty * (bot - top);
}

extern "C" void kernel_launch(void* const* d_in, const int* in_sizes, int n_in,
                              void* d_out, int out_size, void* d_ws, size_t ws_size,
                              hipStream_t stream) {
    const float* points = (const float*)d_in[0];
    int N = in_sizes[0] / 4;
    const float *W[6], *G[6], *B[6];
    for (int i = 0; i < 6; ++i) {
        W[i] = (const float*)d_in[1 + 3 * i];
        G[i] = (const float*)d_in[2 + 3 * i];
        B[i] = (const float*)d_in[3 + 3 * i];
    }

    // ---- workspace layout (bytes), peak ~144 MiB ----
    char* ws = (char*)d_ws;
    const size_t MiB = 1ull << 20;
    unsigned short* gridH = (unsigned short*)(ws);               // f16 (130^3,4) = 17,576,000 B
    unsigned short* O1s = (unsigned short*)(ws + 36 * MiB);      // 65*130*130*32*2 = 70,304,000
    unsigned short* O2p = (unsigned short*)(ws + 104 * MiB);     // 66^3*64*2 = 36,799,488
    unsigned short* O3p = (unsigned short*)(ws);                 // 36,799,488 (over dead gridH)
    unsigned short* O4p = (unsigned short*)(ws + 37 * MiB);      // 34^3*128*2 = 10,061,824
    unsigned short* O5p = (unsigned short*)(ws + 48 * MiB);      // 10,061,824
    unsigned short* O6p = (unsigned short*)(ws + 59 * MiB);      // 34^3*256*2 = 20,123,648
    float* bev = (float*)(ws + 80 * MiB);                        // 1,048,576
    unsigned short* wc1 = (unsigned short*)(ws + 140 * MiB);     // 9,216
    unsigned short* wb2 = (unsigned short*)(ws + 140 * MiB + 16384);
    unsigned short* wb3 = wb2 + 27 * 64 * 32;
    unsigned short* wb4 = wb3 + 27 * 64 * 64;
    unsigned short* wb5 = wb4 + 27 * 128 * 64;
    unsigned short* wb6 = wb5 + 27 * 128 * 128;

    // weight repacks (independent of activations)
    repack_w1m<<<18, 256, 0, stream>>>(W[0], G[0], wc1);
    repack_w<<<216, 256, 0, stream>>>(W[1], G[1], wb2, 64, 32);
    repack_w<<<432, 256, 0, stream>>>(W[2], G[2], wb3, 64, 64);
    repack_w<<<864, 256, 0, stream>>>(W[3], G[3], wb4, 128, 64);
    repack_w<<<1728, 256, 0, stream>>>(W[4], G[4], wb5, 128, 128);
    repack_w<<<3456, 256, 0, stream>>>(W[5], G[5], wb6, 256, 128);

    // voxelize (f16 pk atomics) — grid must be fully zeroed for accumulation
    hipMemsetAsync(gridH, 0, 17576000, stream);
    zero_halo<<<817, 256, 0, stream>>>(O2p, 66, 8, 6 * 66 * 66 * 8);
    voxelize_kernel<<<(N + 255) / 256, 256, 0, stream>>>((const float4*)points, (__half2*)gridH, N);

    // O1s: row 0 full zero + y/x shells of all 65 rows
    hipMemsetAsync(O1s, 0, 1081600, stream);
    zero_halo_yx<<<529, 256, 0, stream>>>(O1s, 65, 130, 4, 4 * 65 * 130 * 4);

    // conv1/conv2 in two z-slabs (O1s holds 65 padded-z rows)
    conv1_mfma<<<8192, 256, 0, stream>>>(gridH, wc1, B[0], O1s, 0, 1);
    conv_mfma<32, 32, 2, 64><<<dim3(1, 1024), 256, 0, stream>>>(O1s, wb2, B[1], O2p, 130, 66, 64, 0, 0);
    conv1_mfma<<<8320, 256, 0, stream>>>(gridH, wc1, B[0], O1s, 63, 0);
    conv_mfma<32, 32, 2, 64><<<dim3(1, 1024), 256, 0, stream>>>(O1s, wb2, B[1], O2p, 130, 66, 64, 64, 131072);

    // remaining buffers become free only after conv2-h2 (aliasing over dead gridH/O1s)
    zero_halo<<<817, 256, 0, stream>>>(O3p, 66, 8, 6 * 66 * 66 * 8);
    zero_halo<<<434, 256, 0, stream>>>(O4p, 34, 16, 6 * 34 * 34 * 16);
    zero_halo<<<434, 256, 0, stream>>>(O5p, 34, 16, 6 * 34 * 34 * 16);
    zero_halo<<<868, 256, 0, stream>>>(O6p, 34, 32, 6 * 34 * 34 * 32);

    // conv3: 64->64, s1, 64^3
    conv_mfma<64, 64, 1, 64><<<dim3(1, 2048), 256, 0, stream>>>(O2p, wb3, B[2], O3p, 66, 66, 64, 0, 0);
    // conv4: 64->128, s2, 64^3 -> 32^3
    conv_mfma<64, 32, 2, 32><<<dim3(2, 256), 256, 0, stream>>>(O3p, wb4, B[3], O4p, 66, 34, 128, 0, 0);
    // conv5: 128->128, s1, 32^3
    conv_mfma<128, 64, 1, 32><<<dim3(2, 256), 256, 0, stream>>>(O4p, wb5, B[4], O5p, 34, 34, 128, 0, 0);
    // conv6: 128->256, s1, 32^3
    conv_mfma<128, 64, 1, 32><<<dim3(4, 256), 256, 0, stream>>>(O5p, wb6, B[5], O6p, 34, 34, 256, 0, 0);

    bev_max_kernel<<<1024, 256, 0, stream>>>(O6p, bev);
    resize_kernel<<<40000, 256, 0, stream>>>(bev, (float*)d_out);
}